// Round 6
// baseline (869.086 us; speedup 1.0000x reference)
//
#include <hip/hip_runtime.h>

// ---------------------------------------------------------------------------
// MultiDiscreteACTLayer: B=131072 rows, D=256.
// Per row: 8 users x 16 sc logits + 8 heads x 10 pow logits = 208 dots of 256.
// JAX threefry, PARTITIONABLE semantics (jax>=0.4.36 default):
//   split(key,8)[u] = threefry2x32(key, (0, u))          (foldlike, both words)
//   fold_in(key, d) = threefry2x32(key, (0, d))          (both words)
//   random_bits 32-bit, element i: (b1,b2)=tf2(key,(0,i)); bits = b1 ^ b2
// Output (float32): actions (B,16) | logp_sum (B,1) | avail (B,16).
// R6: f64 MFMA GEMM kept, but the C/D fragment layout is now PROBED at
//     runtime (two label-MFMAs per wave: D=i and D=j) instead of assumed —
//     robust to any row/col lane mapping and any k-permutation (consistent
//     k-permutations of A and B cancel in the dot product).
// ---------------------------------------------------------------------------

#define B_TOTAL 131072
#define NCOL    208      // 8 users * (16 sc + 10 pow)
#define NCOLP   256      // padded column count
#define XPAD    260      // LDS row pitch in floats (bank-conflict pad)
#define TINYF   1.17549435e-38f

typedef double d4 __attribute__((ext_vector_type(4)));

struct TF2 { unsigned a, b; };

__host__ __device__ constexpr unsigned rotl_(unsigned x, int r) {
  return (x << r) | (x >> (32 - r));
}

// Threefry-2x32, 20 rounds, exactly as JAX/Random123.
__host__ __device__ constexpr TF2 tf2(unsigned k0, unsigned k1, unsigned x0, unsigned x1) {
  unsigned ks0 = k0, ks1 = k1, ks2 = k0 ^ k1 ^ 0x1BD11BDAu;
  x0 += ks0; x1 += ks1;
  x0 += x1; x1 = rotl_(x1, 13); x1 ^= x0;
  x0 += x1; x1 = rotl_(x1, 15); x1 ^= x0;
  x0 += x1; x1 = rotl_(x1, 26); x1 ^= x0;
  x0 += x1; x1 = rotl_(x1,  6); x1 ^= x0;
  x0 += ks1; x1 += ks2 + 1u;
  x0 += x1; x1 = rotl_(x1, 17); x1 ^= x0;
  x0 += x1; x1 = rotl_(x1, 29); x1 ^= x0;
  x0 += x1; x1 = rotl_(x1, 16); x1 ^= x0;
  x0 += x1; x1 = rotl_(x1, 24); x1 ^= x0;
  x0 += ks2; x1 += ks0 + 2u;
  x0 += x1; x1 = rotl_(x1, 13); x1 ^= x0;
  x0 += x1; x1 = rotl_(x1, 15); x1 ^= x0;
  x0 += x1; x1 = rotl_(x1, 26); x1 ^= x0;
  x0 += x1; x1 = rotl_(x1,  6); x1 ^= x0;
  x0 += ks0; x1 += ks1 + 3u;
  x0 += x1; x1 = rotl_(x1, 17); x1 ^= x0;
  x0 += x1; x1 = rotl_(x1, 29); x1 ^= x0;
  x0 += x1; x1 = rotl_(x1, 16); x1 ^= x0;
  x0 += x1; x1 = rotl_(x1, 24); x1 ^= x0;
  x0 += ks1; x1 += ks2 + 4u;
  x0 += x1; x1 = rotl_(x1, 13); x1 ^= x0;
  x0 += x1; x1 = rotl_(x1, 15); x1 ^= x0;
  x0 += x1; x1 = rotl_(x1, 26); x1 ^= x0;
  x0 += x1; x1 = rotl_(x1,  6); x1 ^= x0;
  x0 += ks2; x1 += ks0 + 5u;
  return TF2{x0, x1};
}

// foldlike derivation from root key (0, 42)
__host__ __device__ constexpr unsigned key_a(unsigned d) { return tf2(0u, 42u, 0u, d).a; }
__host__ __device__ constexpr unsigned key_b(unsigned d) { return tf2(0u, 42u, 0u, d).b; }

// sc_keys[u] = split(key(42), 8)[u]  (partitionable/foldlike)
__device__ const unsigned g_SK0[8] = {
  key_a(0), key_a(1), key_a(2), key_a(3), key_a(4), key_a(5), key_a(6), key_a(7)
};
__device__ const unsigned g_SK1[8] = {
  key_b(0), key_b(1), key_b(2), key_b(3), key_b(4), key_b(5), key_b(6), key_b(7)
};
// pow_key = fold_in(key(42), 999)
constexpr unsigned PK0 = key_a(999);
constexpr unsigned PK1 = key_b(999);

// JAX gumbel from raw bits, fp32 ops replicated; logs via double (correctly
// rounded fp32 result).
__device__ __forceinline__ float gumbelf(unsigned bits) {
  float u = __uint_as_float((bits >> 9) | 0x3f800000u) - 1.0f;   // [0,1)
  u = u + TINYF;               // u*(1-tiny)+tiny with (1-tiny)==1.0f in fp32
  u = fmaxf(TINYF, u);
  float nl = -(float)log((double)u);       // -log(u) > 0
  return -(float)log((double)nl);
}

// ---------------------------------------------------------------------------
// Kernel 0: repack W_sc (8,256,16) + W_pow (8,256,10) -> Wp[k][c], c in [0,256)
// (cols 208..255 zero), plus packed bias bp[256]. Column c = u*26 + n,
// n<16 -> sc logit n, n in 16..25 -> pow logit n-16.
// ---------------------------------------------------------------------------
__global__ void repack_kernel(const float* __restrict__ Wsc, const float* __restrict__ bsc,
                              const float* __restrict__ Wpow, const float* __restrict__ bpow,
                              float* __restrict__ Wp, float* __restrict__ bp) {
  int t = blockIdx.x * 256 + threadIdx.x;   // [0, 65792)
  if (t < 65536) {
    int k = t >> 8, c = t & 255;
    float v = 0.f;
    if (c < NCOL) {
      int u = c / 26, n = c % 26;
      v = (n < 16) ? Wsc[(u * 256 + k) * 16 + n]
                   : Wpow[(u * 256 + k) * 10 + (n - 16)];
    }
    Wp[k * NCOLP + c] = v;
  } else {
    int c = t - 65536;
    float v = 0.f;
    if (c < NCOL) {
      int u = c / 26, n = c % 26;
      v = (n < 16) ? bsc[u * 16 + n] : bpow[u * 10 + (n - 16)];
    }
    bp[c] = v;
  }
}

// ---------------------------------------------------------------------------
// Main kernel: each block handles 16 consecutive rows.
// Phase A: DGEMM via v_mfma_f64_16x16x4_f64. Wave w owns cols [64w, 64w+64):
//          4 tiles of 16 cols. A fragment: x[r16][k4+q]; B: Wp[k4+q][col].
//          D layout determined by runtime probes (see header comment).
// Phase B: threefry+gumbel into LDS (gg aliases xs, dead after Phase A).
// Phase C: 16 lanes per row: sc masked scan (8 users) + pow heads (8).
// ---------------------------------------------------------------------------
__global__ __launch_bounds__(256) void act_kernel(
    const float* __restrict__ x, const int* __restrict__ avail,
    const float* __restrict__ Wp, const float* __restrict__ bp,
    float* __restrict__ out) {
  __shared__ __align__(16) union SMem {
    float xs[16][XPAD];    // 16.25 KB (Phase A; padded pitch)
    float gg[16][NCOL];    // 13.3 KB (Phase B/C)
  } sm;
  __shared__ float lg[16][NCOL];

  const int t = threadIdx.x;
  const int b0 = blockIdx.x * 16;

  // ---- load x tile (16 rows x 256) as float4 into padded LDS rows ----
#pragma unroll
  for (int i = 0; i < 4; ++i) {
    int flat = t + 256 * i;            // float4 index, [0,1024)
    int r = flat >> 6;                 // 64 float4 per row
    int kq = flat & 63;
    ((float4*)(&sm.xs[r][0]))[kq] = ((const float4*)(x + (size_t)(b0 + r) * 256))[kq];
  }
  __syncthreads();

  // ---- Phase A: fp64 MFMA GEMM ----
  {
    const int lane = t & 63;
    const int wv   = t >> 6;           // wave 0..3
    const int q    = lane >> 4;        // k-slot 0..3 (assumed; probe-robust)
    const int r16  = lane & 15;        // row/col label within 16
    const int col0 = wv * 64;

    const d4 dzero = {0.0, 0.0, 0.0, 0.0};
    d4 acc0 = dzero, acc1 = dzero, acc2 = dzero, acc3 = dzero;

    // B pointer: Wp[(k4+q)*256 + col0 + r16], tiles at +16j, step +4 rows.
    const float* wq = Wp + q * NCOLP + col0 + r16;
#pragma unroll 2
    for (int k4 = 0; k4 < 256; k4 += 4) {
      float  bf0 = wq[0], bf1 = wq[16], bf2 = wq[32], bf3 = wq[48];
      double a   = (double)sm.xs[r16][k4 + q];
      wq += 4 * NCOLP;
      acc0 = __builtin_amdgcn_mfma_f64_16x16x4f64(a, (double)bf0, acc0, 0, 0, 0);
      acc1 = __builtin_amdgcn_mfma_f64_16x16x4f64(a, (double)bf1, acc1, 0, 0, 0);
      acc2 = __builtin_amdgcn_mfma_f64_16x16x4f64(a, (double)bf2, acc2, 0, 0, 0);
      acc3 = __builtin_amdgcn_mfma_f64_16x16x4f64(a, (double)bf3, acc3, 0, 0, 0);
    }

    // ---- layout probes: D=i (row labels) and D=j (col labels) ----
    // Single nonzero k-slot (q==0); any consistent k-permutation lands both
    // A and B labels on the same HW k, so the product is layout-invariant.
    {
      double sel = (q == 0) ? 1.0 : 0.0;
      d4 pr = __builtin_amdgcn_mfma_f64_16x16x4f64(sel * (double)r16, sel, dzero, 0, 0, 0);
      d4 pc = __builtin_amdgcn_mfma_f64_16x16x4f64(sel, sel * (double)r16, dzero, 0, 0, 0);
      // epilogue: scatter acc*[r] to probed (row, col)
#pragma unroll
      for (int r = 0; r < 4; ++r) {
        int i    = ((int)(pr[r] + 0.5)) & 15;   // x-row label at (lane, reg r)
        int joff = ((int)(pc[r] + 0.5)) & 15;   // within-tile col label
        int c0 = col0 + joff;
        if (c0 +  0 < NCOL) lg[i][c0 +  0] = (float)(acc0[r] + (double)bp[c0 +  0]);
        if (c0 + 16 < NCOL) lg[i][c0 + 16] = (float)(acc1[r] + (double)bp[c0 + 16]);
        if (c0 + 32 < NCOL) lg[i][c0 + 32] = (float)(acc2[r] + (double)bp[c0 + 32]);
        if (c0 + 48 < NCOL) lg[i][c0 + 48] = (float)(acc3[r] + (double)bp[c0 + 48]);
      }
    }
  }
  __syncthreads();   // all xs reads done before gg (aliased) is written

  // ---- Phase B: gumbels, partitionable counter mode (bits = w0 ^ w1) ----
  // 16 rows x 208 cols = 3328 = 13 * 256 elements.
  // sc element (user u, row gb, cat n):   i = gb*16+n,        key SK[u]
  // pow element (row gb, head h, cat j):  i = gb*80+h*10+j,   key PK
#pragma unroll
  for (int i = 0; i < 13; ++i) {
    int idx = t + 256 * i;             // [0, 3328)
    int row = idx / 208, c = idx % 208;
    int u = c / 26, n = c % 26;
    unsigned gbr = (unsigned)(b0 + row);
    unsigned k0, k1, cnt;
    if (n < 16) { k0 = g_SK0[u]; k1 = g_SK1[u]; cnt = gbr * 16u + (unsigned)n; }
    else        { k0 = PK0;      k1 = PK1;      cnt = gbr * 80u + (unsigned)(u * 10 + n - 16); }
    TF2 r = tf2(k0, k1, 0u, cnt);
    sm.gg[row][c] = gumbelf(r.a ^ r.b);
  }
  __syncthreads();

  // ---- Phase C: sampling. 16 lanes per row. ----
  const int row = t >> 4;
  const int lane = t & 15;
  const int gb = b0 + row;
  const int av = avail[gb * 16 + lane];   // my lane's avail column
  int stat = 0;                           // sc_stat for category `lane`
  double lpsum = 0.0;
  float my_act = 0.0f;

  // sc scan: 8 users, sequential (sc_stat dependency)
  for (int u = 0; u < 8; ++u) {
    float logit = lg[row][u * 26 + lane];
    float ml = (stat < 2) ? logit : -1e10f;          // masked logit
    float y = ml + sm.gg[row][u * 26 + lane];        // gumbel-perturbed
    // argmax (first index on tie)
    float v = y; int idx = lane;
    for (int off = 8; off; off >>= 1) {
      float v2 = __shfl_xor(v, off, 16);
      int i2 = __shfl_xor(idx, off, 16);
      if (v2 > v || (v2 == v && i2 < idx)) { v = v2; idx = i2; }
    }
    // log-softmax denom over masked logits
    float m = ml;
    for (int off = 8; off; off >>= 1) m = fmaxf(m, __shfl_xor(m, off, 16));
    float sh = ml - m;                               // fp32 shifted
    double s = exp((double)sh);                      // exp(-1e10)=0 for masked
    for (int off = 8; off; off >>= 1) s += __shfl_xor(s, off, 16);
    float sha = __shfl(sh, idx, 16);
    double lp = (double)sha - log(s);
    int au = __shfl(av, u, 16);
    if (au > 0) {
      lpsum += lp;
      if (lane == idx) stat += 1;                    // sc_stat update
    }
    if (lane == u) my_act = (au > 0) ? (float)idx : -1.0f;
  }

  // pow heads: independent
  for (int h = 0; h < 8; ++h) {
    bool on = lane < 10;
    float logit = on ? lg[row][h * 26 + 16 + lane] : -3.0e38f;
    float y = on ? (logit + sm.gg[row][h * 26 + 16 + lane]) : -3.0e38f;
    float v = y; int idx = lane;
    for (int off = 8; off; off >>= 1) {
      float v2 = __shfl_xor(v, off, 16);
      int i2 = __shfl_xor(idx, off, 16);
      if (v2 > v || (v2 == v && i2 < idx)) { v = v2; idx = i2; }
    }
    float m = logit;
    for (int off = 8; off; off >>= 1) m = fmaxf(m, __shfl_xor(m, off, 16));
    float sh = logit - m;
    double s = on ? exp((double)sh) : 0.0;
    for (int off = 8; off; off >>= 1) s += __shfl_xor(s, off, 16);
    float sha = __shfl(sh, idx, 16);
    double lp = (double)sha - log(s);
    int ah = __shfl(av, 8 + h, 16);
    if (ah > 0) lpsum += lp;
    if (lane == 8 + h) my_act = (ah > 0) ? (float)idx : -1.0f;
  }

  // ---- stores (all float32) ----
  out[(size_t)gb * 16 + lane] = my_act;                                // actions
  if (lane == 0) out[(size_t)B_TOTAL * 16 + gb] = (float)lpsum;        // logp sum
  out[(size_t)B_TOTAL * 17 + (size_t)gb * 16 + lane] = (float)av;      // avail
}

extern "C" void kernel_launch(void* const* d_in, const int* in_sizes, int n_in,
                              void* d_out, int out_size, void* d_ws, size_t ws_size,
                              hipStream_t stream) {
  const float* x    = (const float*)d_in[0];
  const int*   av   = (const int*)  d_in[1];
  const float* Wsc  = (const float*)d_in[2];
  const float* bsc  = (const float*)d_in[3];
  const float* Wpow = (const float*)d_in[4];
  const float* bpow = (const float*)d_in[5];
  float* outp = (float*)d_out;

  float* Wp = (float*)d_ws;          // 256*256 floats
  float* bp = Wp + 65536;            // 256 floats

  repack_kernel<<<257, 256, 0, stream>>>(Wsc, bsc, Wpow, bpow, Wp, bp);
  act_kernel<<<B_TOTAL / 16, 256, 0, stream>>>(x, av, Wp, bp, outp);
}

// Round 7
// 666.314 us; speedup vs baseline: 1.3043x; 1.3043x over previous
//
#include <hip/hip_runtime.h>

// ---------------------------------------------------------------------------
// MultiDiscreteACTLayer: B=131072 rows, D=256.
// Per row: 8 users x 16 sc logits + 8 heads x 10 pow logits = 208 dots of 256.
// JAX threefry, PARTITIONABLE semantics (jax>=0.4.36 default):
//   split(key,8)[u] = threefry2x32(key, (0, u))          (foldlike, both words)
//   fold_in(key, d) = threefry2x32(key, (0, d))          (both words)
//   random_bits 32-bit, element i: (b1,b2)=tf2(key,(0,i)); bits = b1 ^ b2
// Output (float32): actions (B,16) | logp_sum (B,1) | avail (B,16).
// R7: transcendental diet. Phase C (logp-only) uses fp32 hw exp/log;
//     gumbel uses a custom fp64 log (atanh series, ~1e-15 rel) instead of
//     ocml log — actions path keeps fp64-grade precision at ~1/4 the cost.
// ---------------------------------------------------------------------------

#define B_TOTAL 131072
#define NCOL    208      // 8 users * (16 sc + 10 pow)
#define NCOLP   256      // padded column count
#define XPAD    260      // LDS row pitch in floats (bank-conflict pad)
#define TINYF   1.17549435e-38f

typedef double d4 __attribute__((ext_vector_type(4)));

struct TF2 { unsigned a, b; };

__host__ __device__ constexpr unsigned rotl_(unsigned x, int r) {
  return (x << r) | (x >> (32 - r));
}

// Threefry-2x32, 20 rounds, exactly as JAX/Random123.
__host__ __device__ constexpr TF2 tf2(unsigned k0, unsigned k1, unsigned x0, unsigned x1) {
  unsigned ks0 = k0, ks1 = k1, ks2 = k0 ^ k1 ^ 0x1BD11BDAu;
  x0 += ks0; x1 += ks1;
  x0 += x1; x1 = rotl_(x1, 13); x1 ^= x0;
  x0 += x1; x1 = rotl_(x1, 15); x1 ^= x0;
  x0 += x1; x1 = rotl_(x1, 26); x1 ^= x0;
  x0 += x1; x1 = rotl_(x1,  6); x1 ^= x0;
  x0 += ks1; x1 += ks2 + 1u;
  x0 += x1; x1 = rotl_(x1, 17); x1 ^= x0;
  x0 += x1; x1 = rotl_(x1, 29); x1 ^= x0;
  x0 += x1; x1 = rotl_(x1, 16); x1 ^= x0;
  x0 += x1; x1 = rotl_(x1, 24); x1 ^= x0;
  x0 += ks2; x1 += ks0 + 2u;
  x0 += x1; x1 = rotl_(x1, 13); x1 ^= x0;
  x0 += x1; x1 = rotl_(x1, 15); x1 ^= x0;
  x0 += x1; x1 = rotl_(x1, 26); x1 ^= x0;
  x0 += x1; x1 = rotl_(x1,  6); x1 ^= x0;
  x0 += ks0; x1 += ks1 + 3u;
  x0 += x1; x1 = rotl_(x1, 17); x1 ^= x0;
  x0 += x1; x1 = rotl_(x1, 29); x1 ^= x0;
  x0 += x1; x1 = rotl_(x1, 16); x1 ^= x0;
  x0 += x1; x1 = rotl_(x1, 24); x1 ^= x0;
  x0 += ks1; x1 += ks2 + 4u;
  x0 += x1; x1 = rotl_(x1, 13); x1 ^= x0;
  x0 += x1; x1 = rotl_(x1, 15); x1 ^= x0;
  x0 += x1; x1 = rotl_(x1, 26); x1 ^= x0;
  x0 += x1; x1 = rotl_(x1,  6); x1 ^= x0;
  x0 += ks2; x1 += ks0 + 5u;
  return TF2{x0, x1};
}

// foldlike derivation from root key (0, 42)
__host__ __device__ constexpr unsigned key_a(unsigned d) { return tf2(0u, 42u, 0u, d).a; }
__host__ __device__ constexpr unsigned key_b(unsigned d) { return tf2(0u, 42u, 0u, d).b; }

// sc_keys[u] = split(key(42), 8)[u]  (partitionable/foldlike)
__device__ const unsigned g_SK0[8] = {
  key_a(0), key_a(1), key_a(2), key_a(3), key_a(4), key_a(5), key_a(6), key_a(7)
};
__device__ const unsigned g_SK1[8] = {
  key_b(0), key_b(1), key_b(2), key_b(3), key_b(4), key_b(5), key_b(6), key_b(7)
};
// pow_key = fold_in(key(42), 999)
constexpr unsigned PK0 = key_a(999);
constexpr unsigned PK1 = key_b(999);

// Fast fp64 natural log for positive normal inputs (no edge handling).
// Range reduction to m in [sqrt(1/2), sqrt(2)), atanh series in
// r=(m-1)/(m+1); |r|<=0.1716, truncation ~1e-12 rel, total ~1e-15.
__device__ __forceinline__ double dlog(double xd) {
  long long b = __double_as_longlong(xd);
  int e = (int)((b >> 52) & 0x7FF) - 1023;
  double m = __longlong_as_double((b & 0x000FFFFFFFFFFFFFLL) | 0x3FF0000000000000LL);
  if (m > 1.4142135623730951) { m *= 0.5; e += 1; }
  double r  = (m - 1.0) / (m + 1.0);
  double r2 = r * r;
  double p = fma(r2, fma(r2, fma(r2, fma(r2, fma(r2, fma(r2,
              1.0/15.0, 1.0/13.0), 1.0/11.0), 1.0/9.0), 1.0/7.0), 1.0/5.0), 1.0/3.0);
  double lm = fma(2.0 * r, r2 * p, 2.0 * r);
  return fma((double)e, 0.6931471805599453, lm);
}

// JAX gumbel from raw bits, fp32 ops replicated; logs in fp64 via dlog
// (error ~1e-15, far below the f32 storage noise of the result).
__device__ __forceinline__ float gumbelf(unsigned bits) {
  float u = __uint_as_float((bits >> 9) | 0x3f800000u) - 1.0f;   // [0,1)
  u = u + TINYF;               // u*(1-tiny)+tiny with (1-tiny)==1.0f in fp32
  u = fmaxf(TINYF, u);
  double nl = -dlog((double)u);            // in (5.9e-8, 87.4] — normal
  return -(float)dlog(nl);
}

// ---------------------------------------------------------------------------
// Kernel 0: repack W_sc (8,256,16) + W_pow (8,256,10) -> Wp[k][c], c in [0,256)
// (cols 208..255 zero), plus packed bias bp[256]. Column c = u*26 + n,
// n<16 -> sc logit n, n in 16..25 -> pow logit n-16.
// ---------------------------------------------------------------------------
__global__ void repack_kernel(const float* __restrict__ Wsc, const float* __restrict__ bsc,
                              const float* __restrict__ Wpow, const float* __restrict__ bpow,
                              float* __restrict__ Wp, float* __restrict__ bp) {
  int t = blockIdx.x * 256 + threadIdx.x;   // [0, 65792)
  if (t < 65536) {
    int k = t >> 8, c = t & 255;
    float v = 0.f;
    if (c < NCOL) {
      int u = c / 26, n = c % 26;
      v = (n < 16) ? Wsc[(u * 256 + k) * 16 + n]
                   : Wpow[(u * 256 + k) * 10 + (n - 16)];
    }
    Wp[k * NCOLP + c] = v;
  } else {
    int c = t - 65536;
    float v = 0.f;
    if (c < NCOL) {
      int u = c / 26, n = c % 26;
      v = (n < 16) ? bsc[u * 16 + n] : bpow[u * 10 + (n - 16)];
    }
    bp[c] = v;
  }
}

// ---------------------------------------------------------------------------
// Main kernel: each block handles 16 consecutive rows.
// Phase A: DGEMM via v_mfma_f64_16x16x4_f64 with runtime layout probes.
// Phase B: threefry+gumbel into LDS (gg aliases xs, dead after Phase A).
// Phase C: 16 lanes per row: sc masked scan (8 users) + pow heads (8);
//          logp math in fp32 (hw exp/log) — actions don't touch it.
// ---------------------------------------------------------------------------
__global__ __launch_bounds__(256) void act_kernel(
    const float* __restrict__ x, const int* __restrict__ avail,
    const float* __restrict__ Wp, const float* __restrict__ bp,
    float* __restrict__ out) {
  __shared__ __align__(16) union SMem {
    float xs[16][XPAD];    // 16.25 KB (Phase A; padded pitch)
    float gg[16][NCOL];    // 13.3 KB (Phase B/C)
  } sm;
  __shared__ float lg[16][NCOL];

  const int t = threadIdx.x;
  const int b0 = blockIdx.x * 16;

  // ---- load x tile (16 rows x 256) as float4 into padded LDS rows ----
#pragma unroll
  for (int i = 0; i < 4; ++i) {
    int flat = t + 256 * i;            // float4 index, [0,1024)
    int r = flat >> 6;                 // 64 float4 per row
    int kq = flat & 63;
    ((float4*)(&sm.xs[r][0]))[kq] = ((const float4*)(x + (size_t)(b0 + r) * 256))[kq];
  }
  __syncthreads();

  // ---- Phase A: fp64 MFMA GEMM ----
  {
    const int lane = t & 63;
    const int wv   = t >> 6;           // wave 0..3
    const int q    = lane >> 4;        // k-slot 0..3 (assumed; probe-robust)
    const int r16  = lane & 15;        // row/col label within 16
    const int col0 = wv * 64;

    const d4 dzero = {0.0, 0.0, 0.0, 0.0};
    d4 acc0 = dzero, acc1 = dzero, acc2 = dzero, acc3 = dzero;

    // B pointer: Wp[(k4+q)*256 + col0 + r16], tiles at +16j, step +4 rows.
    const float* wq = Wp + q * NCOLP + col0 + r16;
#pragma unroll 2
    for (int k4 = 0; k4 < 256; k4 += 4) {
      float  bf0 = wq[0], bf1 = wq[16], bf2 = wq[32], bf3 = wq[48];
      double a   = (double)sm.xs[r16][k4 + q];
      wq += 4 * NCOLP;
      acc0 = __builtin_amdgcn_mfma_f64_16x16x4f64(a, (double)bf0, acc0, 0, 0, 0);
      acc1 = __builtin_amdgcn_mfma_f64_16x16x4f64(a, (double)bf1, acc1, 0, 0, 0);
      acc2 = __builtin_amdgcn_mfma_f64_16x16x4f64(a, (double)bf2, acc2, 0, 0, 0);
      acc3 = __builtin_amdgcn_mfma_f64_16x16x4f64(a, (double)bf3, acc3, 0, 0, 0);
    }

    // ---- layout probes: D=i (row labels) and D=j (col labels) ----
    {
      double sel = (q == 0) ? 1.0 : 0.0;
      d4 pr = __builtin_amdgcn_mfma_f64_16x16x4f64(sel * (double)r16, sel, dzero, 0, 0, 0);
      d4 pc = __builtin_amdgcn_mfma_f64_16x16x4f64(sel, sel * (double)r16, dzero, 0, 0, 0);
#pragma unroll
      for (int r = 0; r < 4; ++r) {
        int i    = ((int)(pr[r] + 0.5)) & 15;   // x-row label at (lane, reg r)
        int joff = ((int)(pc[r] + 0.5)) & 15;   // within-tile col label
        int c0 = col0 + joff;
        if (c0 +  0 < NCOL) lg[i][c0 +  0] = (float)(acc0[r] + (double)bp[c0 +  0]);
        if (c0 + 16 < NCOL) lg[i][c0 + 16] = (float)(acc1[r] + (double)bp[c0 + 16]);
        if (c0 + 32 < NCOL) lg[i][c0 + 32] = (float)(acc2[r] + (double)bp[c0 + 32]);
        if (c0 + 48 < NCOL) lg[i][c0 + 48] = (float)(acc3[r] + (double)bp[c0 + 48]);
      }
    }
  }
  __syncthreads();   // all xs reads done before gg (aliased) is written

  // ---- Phase B: gumbels, partitionable counter mode (bits = w0 ^ w1) ----
  // 16 rows x 208 cols = 3328 = 13 * 256 elements.
  // sc element (user u, row gb, cat n):   i = gb*16+n,        key SK[u]
  // pow element (row gb, head h, cat j):  i = gb*80+h*10+j,   key PK
#pragma unroll
  for (int i = 0; i < 13; ++i) {
    int idx = t + 256 * i;             // [0, 3328)
    int row = idx / 208, c = idx % 208;
    int u = c / 26, n = c % 26;
    unsigned gbr = (unsigned)(b0 + row);
    unsigned k0, k1, cnt;
    if (n < 16) { k0 = g_SK0[u]; k1 = g_SK1[u]; cnt = gbr * 16u + (unsigned)n; }
    else        { k0 = PK0;      k1 = PK1;      cnt = gbr * 80u + (unsigned)(u * 10 + n - 16); }
    TF2 r = tf2(k0, k1, 0u, cnt);
    sm.gg[row][c] = gumbelf(r.a ^ r.b);
  }
  __syncthreads();

  // ---- Phase C: sampling. 16 lanes per row. ----
  const int row = t >> 4;
  const int lane = t & 15;
  const int gb = b0 + row;
  const int av = avail[gb * 16 + lane];   // my lane's avail column
  int stat = 0;                           // sc_stat for category `lane`
  float lpsum = 0.0f;
  float my_act = 0.0f;

  // sc scan: 8 users, sequential (sc_stat dependency)
  for (int u = 0; u < 8; ++u) {
    float logit = lg[row][u * 26 + lane];
    float ml = (stat < 2) ? logit : -1e10f;          // masked logit
    float y = ml + sm.gg[row][u * 26 + lane];        // gumbel-perturbed
    // argmax (first index on tie) — actions path, fp32 only
    float v = y; int idx = lane;
    for (int off = 8; off; off >>= 1) {
      float v2 = __shfl_xor(v, off, 16);
      int i2 = __shfl_xor(idx, off, 16);
      if (v2 > v || (v2 == v && i2 < idx)) { v = v2; idx = i2; }
    }
    // log-softmax denom (logp-only; fp32 hw exp/log)
    float m = ml;
    for (int off = 8; off; off >>= 1) m = fmaxf(m, __shfl_xor(m, off, 16));
    float sh = ml - m;
    float s = __expf(sh);                            // masked -> ~exp(-1e10)=0
    for (int off = 8; off; off >>= 1) s += __shfl_xor(s, off, 16);
    float sha = __shfl(sh, idx, 16);
    float lp = sha - __logf(s);
    int au = __shfl(av, u, 16);
    if (au > 0) {
      lpsum += lp;
      if (lane == idx) stat += 1;                    // sc_stat update
    }
    if (lane == u) my_act = (au > 0) ? (float)idx : -1.0f;
  }

  // pow heads: independent
  for (int h = 0; h < 8; ++h) {
    bool on = lane < 10;
    float logit = on ? lg[row][h * 26 + 16 + lane] : -3.0e38f;
    float y = on ? (logit + sm.gg[row][h * 26 + 16 + lane]) : -3.0e38f;
    float v = y; int idx = lane;
    for (int off = 8; off; off >>= 1) {
      float v2 = __shfl_xor(v, off, 16);
      int i2 = __shfl_xor(idx, off, 16);
      if (v2 > v || (v2 == v && i2 < idx)) { v = v2; idx = i2; }
    }
    float m = logit;
    for (int off = 8; off; off >>= 1) m = fmaxf(m, __shfl_xor(m, off, 16));
    float sh = logit - m;
    float s = on ? __expf(sh) : 0.0f;
    for (int off = 8; off; off >>= 1) s += __shfl_xor(s, off, 16);
    float sha = __shfl(sh, idx, 16);
    float lp = sha - __logf(s);
    int ah = __shfl(av, 8 + h, 16);
    if (ah > 0) lpsum += lp;
    if (lane == 8 + h) my_act = (ah > 0) ? (float)idx : -1.0f;
  }

  // ---- stores (all float32) ----
  out[(size_t)gb * 16 + lane] = my_act;                                // actions
  if (lane == 0) out[(size_t)B_TOTAL * 16 + gb] = lpsum;               // logp sum
  out[(size_t)B_TOTAL * 17 + (size_t)gb * 16 + lane] = (float)av;      // avail
}

extern "C" void kernel_launch(void* const* d_in, const int* in_sizes, int n_in,
                              void* d_out, int out_size, void* d_ws, size_t ws_size,
                              hipStream_t stream) {
  const float* x    = (const float*)d_in[0];
  const int*   av   = (const int*)  d_in[1];
  const float* Wsc  = (const float*)d_in[2];
  const float* bsc  = (const float*)d_in[3];
  const float* Wpow = (const float*)d_in[4];
  const float* bpow = (const float*)d_in[5];
  float* outp = (float*)d_out;

  float* Wp = (float*)d_ws;          // 256*256 floats
  float* bp = Wp + 65536;            // 256 floats

  repack_kernel<<<257, 256, 0, stream>>>(Wsc, bsc, Wpow, bpow, Wp, bp);
  act_kernel<<<B_TOTAL / 16, 256, 0, stream>>>(x, av, Wp, bp, outp);
}

// Round 8
// 597.391 us; speedup vs baseline: 1.4548x; 1.1154x over previous
//
#include <hip/hip_runtime.h>

// ---------------------------------------------------------------------------
// MultiDiscreteACTLayer: B=131072 rows, D=256.
// Per row: 8 users x 16 sc logits + 8 heads x 10 pow logits = 208 dots of 256.
// JAX threefry, PARTITIONABLE semantics (jax>=0.4.36 default):
//   split(key,8)[u] = threefry2x32(key, (0, u))          (foldlike, both words)
//   fold_in(key, d) = threefry2x32(key, (0, d))          (both words)
//   random_bits 32-bit, element i: (b1,b2)=tf2(key,(0,i)); bits = b1 ^ b2
// Output (float32): actions (B,16) | logp_sum (B,1) | avail (B,16).
// R8: 13 MFMA tiles (no padded cols; heavy wave rotated by blockIdx&3);
//     Phase B: constant-key sc loop (shift-only indexing), magic-div pow,
//     dlog division -> rcp_f32 seed + 1 fp64 Newton; Phase C: ballot-argmax,
//     no softmax max-shift (logits tiny), ~half the shuffles.
// ---------------------------------------------------------------------------

#define B_TOTAL 131072
#define NCOL    208      // 8 users * (16 sc + 10 pow)
#define NCOLP   256      // Wp row pitch (cols 208..255 zero)
#define XPAD    260      // LDS row pitch in floats (bank-conflict pad)
#define TINYF   1.17549435e-38f

typedef double d4 __attribute__((ext_vector_type(4)));

struct TF2 { unsigned a, b; };

__host__ __device__ constexpr unsigned rotl_(unsigned x, int r) {
  return (x << r) | (x >> (32 - r));
}

// Threefry-2x32, 20 rounds, exactly as JAX/Random123.
__host__ __device__ constexpr TF2 tf2(unsigned k0, unsigned k1, unsigned x0, unsigned x1) {
  unsigned ks0 = k0, ks1 = k1, ks2 = k0 ^ k1 ^ 0x1BD11BDAu;
  x0 += ks0; x1 += ks1;
  x0 += x1; x1 = rotl_(x1, 13); x1 ^= x0;
  x0 += x1; x1 = rotl_(x1, 15); x1 ^= x0;
  x0 += x1; x1 = rotl_(x1, 26); x1 ^= x0;
  x0 += x1; x1 = rotl_(x1,  6); x1 ^= x0;
  x0 += ks1; x1 += ks2 + 1u;
  x0 += x1; x1 = rotl_(x1, 17); x1 ^= x0;
  x0 += x1; x1 = rotl_(x1, 29); x1 ^= x0;
  x0 += x1; x1 = rotl_(x1, 16); x1 ^= x0;
  x0 += x1; x1 = rotl_(x1, 24); x1 ^= x0;
  x0 += ks2; x1 += ks0 + 2u;
  x0 += x1; x1 = rotl_(x1, 13); x1 ^= x0;
  x0 += x1; x1 = rotl_(x1, 15); x1 ^= x0;
  x0 += x1; x1 = rotl_(x1, 26); x1 ^= x0;
  x0 += x1; x1 = rotl_(x1,  6); x1 ^= x0;
  x0 += ks0; x1 += ks1 + 3u;
  x0 += x1; x1 = rotl_(x1, 17); x1 ^= x0;
  x0 += x1; x1 = rotl_(x1, 29); x1 ^= x0;
  x0 += x1; x1 = rotl_(x1, 16); x1 ^= x0;
  x0 += x1; x1 = rotl_(x1, 24); x1 ^= x0;
  x0 += ks1; x1 += ks2 + 4u;
  x0 += x1; x1 = rotl_(x1, 13); x1 ^= x0;
  x0 += x1; x1 = rotl_(x1, 15); x1 ^= x0;
  x0 += x1; x1 = rotl_(x1, 26); x1 ^= x0;
  x0 += x1; x1 = rotl_(x1,  6); x1 ^= x0;
  x0 += ks2; x1 += ks0 + 5u;
  return TF2{x0, x1};
}

// foldlike derivation from root key (0, 42) — all compile-time constants.
__host__ __device__ constexpr unsigned key_a(unsigned d) { return tf2(0u, 42u, 0u, d).a; }
__host__ __device__ constexpr unsigned key_b(unsigned d) { return tf2(0u, 42u, 0u, d).b; }

constexpr unsigned SK0c[8] = {
  key_a(0), key_a(1), key_a(2), key_a(3), key_a(4), key_a(5), key_a(6), key_a(7)
};
constexpr unsigned SK1c[8] = {
  key_b(0), key_b(1), key_b(2), key_b(3), key_b(4), key_b(5), key_b(6), key_b(7)
};
constexpr unsigned PK0 = key_a(999);
constexpr unsigned PK1 = key_b(999);

// Fast fp64 natural log, positive normal inputs. Range-reduce m to
// [sqrt(1/2), sqrt(2)); atanh series in z=(m-1)/(m+1), terms to 1/13
// (trunc ~3e-12 rel); reciprocal via rcp_f32 seed + 1 fp64 Newton
// (~1.4e-14 rel). Total err ~1e-12 — flip-probability analysis: safe.
__device__ __forceinline__ double dlog(double xd) {
  long long b = __double_as_longlong(xd);
  int e = (int)(b >> 52) - 1023;
  double m = __longlong_as_double((b & 0x000FFFFFFFFFFFFFLL) | 0x3FF0000000000000LL);
  if (m > 1.4142135623730951) { m *= 0.5; e += 1; }
  double mp1 = m + 1.0;
  double r = (double)__builtin_amdgcn_rcpf((float)mp1);
  r = fma(fma(-mp1, r, 1.0), r, r);          // 1 Newton: ~1.4e-14 rel
  double z  = (m - 1.0) * r;
  double z2 = z * z;
  double p = fma(z2, fma(z2, fma(z2, fma(z2, fma(z2,
              1.0/13.0, 1.0/11.0), 1.0/9.0), 1.0/7.0), 1.0/5.0), 1.0/3.0);
  double lm = fma(2.0 * z, z2 * p, 2.0 * z);
  return fma((double)e, 0.6931471805599453, lm);
}

// JAX gumbel from raw bits, fp32 bit-ops replicated; logs in fp64 (dlog).
__device__ __forceinline__ float gumbelf(unsigned bits) {
  float u = __uint_as_float((bits >> 9) | 0x3f800000u) - 1.0f;   // [0,1)
  u = u + TINYF;
  u = fmaxf(TINYF, u);
  double nl = -dlog((double)u);            // in (5.9e-8, 87.4] — normal
  return -(float)dlog(nl);
}

// ---------------------------------------------------------------------------
// Kernel 0: repack W_sc (8,256,16) + W_pow (8,256,10) -> Wp[k][c], c in [0,256)
// (cols 208..255 zero), plus packed bias bp[256]. Column c = u*26 + n.
// ---------------------------------------------------------------------------
__global__ void repack_kernel(const float* __restrict__ Wsc, const float* __restrict__ bsc,
                              const float* __restrict__ Wpow, const float* __restrict__ bpow,
                              float* __restrict__ Wp, float* __restrict__ bp) {
  int t = blockIdx.x * 256 + threadIdx.x;   // [0, 65792)
  if (t < 65536) {
    int k = t >> 8, c = t & 255;
    float v = 0.f;
    if (c < NCOL) {
      int u = c / 26, n = c % 26;
      v = (n < 16) ? Wsc[(u * 256 + k) * 16 + n]
                   : Wpow[(u * 256 + k) * 10 + (n - 16)];
    }
    Wp[k * NCOLP + c] = v;
  } else {
    int c = t - 65536;
    float v = 0.f;
    if (c < NCOL) {
      int u = c / 26, n = c % 26;
      v = (n < 16) ? bsc[u * 16 + n] : bpow[u * 10 + (n - 16)];
    }
    bp[c] = v;
  }
}

// ---------------------------------------------------------------------------
// Main kernel: each block handles 16 consecutive rows.
// Phase A: DGEMM via v_mfma_f64_16x16x4_f64, 13 tiles of 16 cols (no pad).
//          Wave wv owns 3 tiles, +1 extra for wv==blockIdx&3 (rotated).
//          D layout resolved by runtime label-probes.
// Phase B: threefry+gumbel into LDS (gg aliases xs; constant-key sc loop).
// Phase C: 16 lanes per row; ballot-argmax; no-max-shift softmax (fp32 hw).
// ---------------------------------------------------------------------------
__global__ __launch_bounds__(256) void act_kernel(
    const float* __restrict__ x, const int* __restrict__ avail,
    const float* __restrict__ Wp, const float* __restrict__ bp,
    float* __restrict__ out) {
  __shared__ __align__(16) union SMem {
    float xs[16][XPAD];    // Phase A (padded pitch)
    float gg[16][NCOL];    // Phase B/C
  } sm;
  __shared__ float lg[16][NCOL];

  const int t = threadIdx.x;
  const int b0 = blockIdx.x * 16;

  // ---- load x tile (16 rows x 256) as float4 into padded LDS rows ----
#pragma unroll
  for (int i = 0; i < 4; ++i) {
    int flat = t + 256 * i;            // float4 index, [0,1024)
    int r = flat >> 6;                 // 64 float4 per row
    int kq = flat & 63;
    ((float4*)(&sm.xs[r][0]))[kq] = ((const float4*)(x + (size_t)(b0 + r) * 256))[kq];
  }
  __syncthreads();

  // ---- Phase A: fp64 MFMA GEMM, 13 tiles ----
  {
    const int lane = t & 63;
    const int wv   = t >> 6;           // wave 0..3
    const int q    = lane >> 4;        // k-slot 0..3
    const int r16  = lane & 15;
    const int h    = blockIdx.x & 3;   // which wave carries the 13th tile
    const bool heavy = (wv == h);
    const int toff = 3 * wv + ((wv > h) ? 1 : 0);   // first owned tile

    const d4 dzero = {0.0, 0.0, 0.0, 0.0};
    d4 acc0 = dzero, acc1 = dzero, acc2 = dzero, acc3 = dzero;

    const float* wq = Wp + q * NCOLP + toff * 16 + r16;
#pragma unroll 2
    for (int k4 = 0; k4 < 256; k4 += 4) {
      float  bf0 = wq[0], bf1 = wq[16], bf2 = wq[32], bf3 = wq[48];
      double a   = (double)sm.xs[r16][k4 + q];
      wq += 4 * NCOLP;
      acc0 = __builtin_amdgcn_mfma_f64_16x16x4f64(a, (double)bf0, acc0, 0, 0, 0);
      acc1 = __builtin_amdgcn_mfma_f64_16x16x4f64(a, (double)bf1, acc1, 0, 0, 0);
      acc2 = __builtin_amdgcn_mfma_f64_16x16x4f64(a, (double)bf2, acc2, 0, 0, 0);
      if (heavy)
        acc3 = __builtin_amdgcn_mfma_f64_16x16x4f64(a, (double)bf3, acc3, 0, 0, 0);
    }

    // ---- layout probes: D=i (row labels) and D=j (col labels) ----
    {
      double sel = (q == 0) ? 1.0 : 0.0;
      d4 pr = __builtin_amdgcn_mfma_f64_16x16x4f64(sel * (double)r16, sel, dzero, 0, 0, 0);
      d4 pc = __builtin_amdgcn_mfma_f64_16x16x4f64(sel, sel * (double)r16, dzero, 0, 0, 0);
#pragma unroll
      for (int r = 0; r < 4; ++r) {
        int i    = ((int)(pr[r] + 0.5)) & 15;   // x-row label at (lane, reg r)
        int joff = ((int)(pc[r] + 0.5)) & 15;   // within-tile col label
        int c0 = toff * 16 + joff;              // all owned cols < 208
        lg[i][c0 +  0] = (float)(acc0[r] + (double)bp[c0 +  0]);
        lg[i][c0 + 16] = (float)(acc1[r] + (double)bp[c0 + 16]);
        lg[i][c0 + 32] = (float)(acc2[r] + (double)bp[c0 + 32]);
        if (heavy)
          lg[i][c0 + 48] = (float)(acc3[r] + (double)bp[c0 + 48]);
      }
    }
  }
  __syncthreads();   // all xs reads done before gg (aliased) is written

  // ---- Phase B: gumbels (bits = w0 ^ w1) ----
  // sc: one element per thread per user; keys are compile-time constants.
  {
    const int prow = t >> 4;           // 0..15
    const int pn   = t & 15;           // category
    const unsigned cnt = (unsigned)((b0 + prow) * 16 + pn);
    float* grow = &sm.gg[prow][pn];
#pragma unroll
    for (int u = 0; u < 8; ++u) {
      TF2 r = tf2(SK0c[u], SK1c[u], 0u, cnt);
      grow[u * 26] = gumbelf(r.a ^ r.b);
    }
  }
  // pow: 16 rows x 80 = 1280 elements, 5 per thread; magic-mul div.
#pragma unroll
  for (int i = 0; i < 5; ++i) {
    int flat = t + 256 * i;                       // [0, 1280)
    int prw  = (flat * 13108) >> 20;              // flat / 80
    int q80  = flat - prw * 80;
    int hh   = (q80 * 103) >> 10;                 // q80 / 10
    int jj   = q80 - hh * 10;
    unsigned cnt = (unsigned)((b0 + prw) * 80 + q80);
    TF2 r = tf2(PK0, PK1, 0u, cnt);
    sm.gg[prw][hh * 26 + 16 + jj] = gumbelf(r.a ^ r.b);
  }
  __syncthreads();

  // ---- Phase C: sampling. 16 lanes per row. ----
  const int row  = t >> 4;
  const int lane = t & 15;
  const int g16  = (t & 63) >> 4;        // 16-lane group within wave
  const int gb   = b0 + row;
  const int av = avail[gb * 16 + lane];
  int stat = 0;
  float lpsum = 0.0f;
  float my_act = 0.0f;

  // sc scan: 8 users, sequential (sc_stat dependency)
  for (int u = 0; u < 8; ++u) {
    float logit = lg[row][u * 26 + lane];
    float ml = (stat < 2) ? logit : -1e10f;
    float y  = ml + sm.gg[row][u * 26 + lane];
    // max + first-index argmax via ballot
    float vmax = y;
    for (int off = 8; off; off >>= 1) vmax = fmaxf(vmax, __shfl_xor(vmax, off, 16));
    unsigned long long bal = __ballot(y == vmax);
    int idx = __builtin_ctzll((bal >> (g16 * 16)) & 0xFFFFull);
    // softmax denom without max-shift (|logit| small; masked exp -> 0)
    float s = __expf(ml);
    for (int off = 8; off; off >>= 1) s += __shfl_xor(s, off, 16);
    float mlidx = __shfl(ml, idx, 16);
    float lp = mlidx - __logf(s);
    int au = __shfl(av, u, 16);
    if (au > 0) {
      lpsum += lp;
      if (lane == idx) stat += 1;
    }
    if (lane == u) my_act = (au > 0) ? (float)idx : -1.0f;
  }

  // pow heads: independent
  for (int h = 0; h < 8; ++h) {
    bool on = lane < 10;
    float logit = on ? lg[row][h * 26 + 16 + lane] : -3.0e38f;
    float y     = on ? (logit + sm.gg[row][h * 26 + 16 + lane]) : -3.0e38f;
    float vmax = y;
    for (int off = 8; off; off >>= 1) vmax = fmaxf(vmax, __shfl_xor(vmax, off, 16));
    unsigned long long bal = __ballot(y == vmax);
    int idx = __builtin_ctzll((bal >> (g16 * 16)) & 0xFFFFull);
    float s = on ? __expf(logit) : 0.0f;
    for (int off = 8; off; off >>= 1) s += __shfl_xor(s, off, 16);
    float mlidx = __shfl(logit, idx, 16);
    float lp = mlidx - __logf(s);
    int ah = __shfl(av, 8 + h, 16);
    if (ah > 0) lpsum += lp;
    if (lane == 8 + h) my_act = (ah > 0) ? (float)idx : -1.0f;
  }

  // ---- stores (all float32) ----
  out[(size_t)gb * 16 + lane] = my_act;                                // actions
  if (lane == 0) out[(size_t)B_TOTAL * 16 + gb] = lpsum;               // logp sum
  out[(size_t)B_TOTAL * 17 + (size_t)gb * 16 + lane] = (float)av;      // avail
}

extern "C" void kernel_launch(void* const* d_in, const int* in_sizes, int n_in,
                              void* d_out, int out_size, void* d_ws, size_t ws_size,
                              hipStream_t stream) {
  const float* x    = (const float*)d_in[0];
  const int*   av   = (const int*)  d_in[1];
  const float* Wsc  = (const float*)d_in[2];
  const float* bsc  = (const float*)d_in[3];
  const float* Wpow = (const float*)d_in[4];
  const float* bpow = (const float*)d_in[5];
  float* outp = (float*)d_out;

  float* Wp = (float*)d_ws;          // 256*256 floats
  float* bp = Wp + 65536;            // 256 floats

  repack_kernel<<<257, 256, 0, stream>>>(Wsc, bsc, Wpow, bpow, Wp, bp);
  act_kernel<<<B_TOTAL / 16, 256, 0, stream>>>(x, av, Wp, bp, outp);
}